// Round 11
// baseline (2096.103 us; speedup 1.0000x reference)
//
#include <hip/hip_runtime.h>

#define NN 50000      // nodes
#define NE 800000     // edges
#define NGR 16        // graphs

typedef unsigned short u16;
typedef unsigned int u32;
typedef __attribute__((ext_vector_type(8))) short bf16x8;
typedef __attribute__((ext_vector_type(4))) float f32x4;

__device__ __forceinline__ u16 f2bf(float f) {       // RNE f32->bf16
  u32 u = __float_as_uint(f);
  return (u16)((u + 0x7fffu + ((u >> 16) & 1u)) >> 16);
}
__device__ __forceinline__ float bflo(u32 v) { return __uint_as_float(v << 16); }
__device__ __forceinline__ float bfhi(u32 v) { return __uint_as_float(v & 0xffff0000u); }

// ---------- degree histogram ----------
__global__ void hist_deg(const int* col, int* deg) {
  int e = blockIdx.x * blockDim.x + threadIdx.x;
  if (e < NE) atomicAdd(&deg[col[e]], 1);
}

// ---------- per-graph counts (sorted ids) + edge segment offsets ----------
__device__ int lbound(const int* a, int n, int v) {
  int lo = 0, hi = n;
  while (lo < hi) { int m = (lo + hi) >> 1; if (a[m] < v) lo = m + 1; else hi = m; }
  return lo;
}
__global__ void count_graphs(const int* batch, const int* ebatch, int* cnt_n, int* cnt_e,
                             int* eoff) {
  int t = threadIdx.x;
  if (t < NGR) cnt_n[t] = lbound(batch, NN, t + 1) - lbound(batch, NN, t);
  else if (t < 2 * NGR) { int g = t - NGR; cnt_e[g] = lbound(ebatch, NE, g + 1) - lbound(ebatch, NE, g); }
  else if (t < 3 * NGR + 1) { int g = t - 2 * NGR; eoff[g] = lbound(ebatch, NE, g); }  // eoff[16]=NE
}

// ---------- exclusive scan of deg -> csr_off (single block) ----------
__global__ __launch_bounds__(256) void scan_deg(const int* deg, int* off) {
  __shared__ int sums[256];
  const int CH = (NN + 255) / 256;
  int t = threadIdx.x;
  int base = t * CH;
  int s = 0;
  for (int i = 0; i < CH; i++) { int idx = base + i; if (idx < NN) s += deg[idx]; }
  sums[t] = s;
  __syncthreads();
  for (int d = 1; d < 256; d <<= 1) {
    int v = (t >= d) ? sums[t - d] : 0;
    __syncthreads();
    sums[t] += v;
    __syncthreads();
  }
  int run = (t == 0) ? 0 : sums[t - 1];
  for (int i = 0; i < CH; i++) { int idx = base + i; if (idx < NN) { off[idx] = run; run += deg[idx]; } }
  if (t == 255) off[NN] = run;
}

// ---------- CSR fill: eid, pos, and CSR-ordered row/graph tables ----------
__global__ void fill_csr(const int* col, const int* rowp, const int* ebatch,
                         const int* off, int* cursor, int* eid, int* pos,
                         int* rowsrt, int* ebs) {
  int e = blockIdx.x * blockDim.x + threadIdx.x;
  if (e < NE) {
    int c = col[e];
    int p = atomicAdd(&cursor[c], 1);
    int slot = off[c] + p;
    eid[slot] = e;
    pos[e] = slot;
    rowsrt[slot] = rowp[e];
    ebs[slot] = ebatch[e];
  }
}

// ---------- weights f32 -> bf16 TRANSPOSED (W1T[l][n][k], W2T[l][n][k]) ----------
__global__ void prep_w_k(const float* W1, const float* W2, u16* W1T, u16* W2T) {
  int i = blockIdx.x * 256 + threadIdx.x;
  if (i < 3 * 128 * 128) {
    int l = i / 16384, k = (i >> 7) & 127, n = i & 127;
    W1T[l * 16384 + n * 128 + k] = f2bf(W1[i]);
  } else {
    int j = i - 3 * 128 * 128;
    if (j < 3 * 128 * 64) {
      int l = j / 8192, k = (j >> 6) & 127, n = j & 63;
      W2T[l * 8192 + n * 128 + k] = f2bf(W2[j]);
    }
  }
}

// ---------- layer-0: segmented ge pool (f32) + CSR permute -> esrt BF16 ----------
__global__ __launch_bounds__(256) void pool_perm_k(const float* __restrict__ ea,
                                                   const int* __restrict__ eoff,
                                                   const int* __restrict__ pos,
                                                   u16* __restrict__ esrt,
                                                   float* __restrict__ gacc, int loff) {
  int gid = blockIdx.x * blockDim.x + threadIdx.x;
  int w = gid >> 6, lane = gid & 63;
  const int NW = (gridDim.x * blockDim.x) >> 6;
  const int CH = (NE + NW - 1) / NW;
  int r0 = w * CH, r1 = min(r0 + CH, NE);
  if (r0 >= r1) return;
  int g = 0;
  while (eoff[g + 1] <= r0) g++;       // <=16 scalar iters, once per wave
  const float* base = ea + lane;
  u16* sbase = esrt + lane;
  while (r0 < r1) {
    int gend = min(r1, eoff[g + 1]);
    float a0 = 0.f, a1 = 0.f, a2 = 0.f, a3 = 0.f;
    float a4 = 0.f, a5 = 0.f, a6 = 0.f, a7 = 0.f;
    int r = r0;
    for (; r + 8 <= gend; r += 8) {
      float v0 = base[(size_t)(r + 0) * 64];
      float v1 = base[(size_t)(r + 1) * 64];
      float v2 = base[(size_t)(r + 2) * 64];
      float v3 = base[(size_t)(r + 3) * 64];
      float v4 = base[(size_t)(r + 4) * 64];
      float v5 = base[(size_t)(r + 5) * 64];
      float v6 = base[(size_t)(r + 6) * 64];
      float v7 = base[(size_t)(r + 7) * 64];
      sbase[(size_t)pos[r + 0] * 64] = f2bf(v0);
      sbase[(size_t)pos[r + 1] * 64] = f2bf(v1);
      sbase[(size_t)pos[r + 2] * 64] = f2bf(v2);
      sbase[(size_t)pos[r + 3] * 64] = f2bf(v3);
      sbase[(size_t)pos[r + 4] * 64] = f2bf(v4);
      sbase[(size_t)pos[r + 5] * 64] = f2bf(v5);
      sbase[(size_t)pos[r + 6] * 64] = f2bf(v6);
      sbase[(size_t)pos[r + 7] * 64] = f2bf(v7);
      a0 += v0; a1 += v1; a2 += v2; a3 += v3;
      a4 += v4; a5 += v5; a6 += v6; a7 += v7;
    }
    for (; r < gend; r++) {
      float v = base[(size_t)r * 64];
      sbase[(size_t)pos[r] * 64] = f2bf(v);
      a0 += v;
    }
    float s = ((a0 + a1) + (a2 + a3)) + ((a4 + a5) + (a6 + a7));
    atomicAdd(&gacc[g * 256 + loff + lane], s);
    r0 = gend;
    g++;
  }
}

// ---------- STREAMING gather (bf16): lane = col-pair, half-wave = row slot ----------
__global__ __launch_bounds__(256) void gather_seq_k(
    const u16* __restrict__ esrt, const int* __restrict__ off,
    const int* __restrict__ batch, u16* __restrict__ hbuf,
    float* __restrict__ gacc, int loff, int store_h) {
  int gid = blockIdx.x * blockDim.x + threadIdx.x;
  int w = gid >> 6, lane = gid & 63;
  const int NW = (gridDim.x * blockDim.x) >> 6;
  const int CHN = (NN + NW - 1) / NW;
  int n0 = w * CHN, n1 = min(n0 + CHN, NN);
  if (n0 >= n1) return;
  int h = lane >> 5, c2 = lane & 31;       // col pair (2*c2, 2*c2+1)
  const u32* base = (const u32*)esrt + c2; // row stride = 32 u32
  int cg = batch[n0];
  float gsx = 0.f, gsy = 0.f;
  for (int n = n0; n < n1; n++) {
    int s = off[n], e = off[n + 1];
    float x0 = 0.f, y0 = 0.f, x1 = 0.f, y1 = 0.f;
    float x2 = 0.f, y2 = 0.f, x3 = 0.f, y3 = 0.f;
    int i = s;
    for (; i + 8 <= e; i += 8) {           // 8 rows/iter, this half loads 4
      u32 v0 = base[(size_t)(i + 0 + h) * 32];
      u32 v1 = base[(size_t)(i + 2 + h) * 32];
      u32 v2 = base[(size_t)(i + 4 + h) * 32];
      u32 v3 = base[(size_t)(i + 6 + h) * 32];
      x0 += bflo(v0); y0 += bfhi(v0);
      x1 += bflo(v1); y1 += bfhi(v1);
      x2 += bflo(v2); y2 += bfhi(v2);
      x3 += bflo(v3); y3 += bfhi(v3);
    }
    for (; i + 2 <= e; i += 2) {
      u32 v = base[(size_t)(i + h) * 32];
      x0 += bflo(v); y0 += bfhi(v);
    }
    if (i < e && h == 0) {
      u32 v = base[(size_t)i * 32];
      x0 += bflo(v); y0 += bfhi(v);
    }
    float sx = (x0 + x1) + (x2 + x3);
    float sy = (y0 + y1) + (y2 + y3);
    sx += __shfl_xor(sx, 32);
    sy += __shfl_xor(sy, 32);
    if (h == 0) {
      float inv = 1.f / (float)max(e - s, 1);
      float hx = sx * inv, hy = sy * inv;
      if (store_h)
        ((u32*)hbuf)[(size_t)n * 32 + c2] = (u32)f2bf(hx) | ((u32)f2bf(hy) << 16);
      int g = batch[n];                    // uniform scalar load
      if (g != cg) {
        float* dst = gacc + cg * 256 + loff + c2 * 2;
        atomicAdd(dst + 0, gsx);
        atomicAdd(dst + 1, gsy);
        gsx = 0.f; gsy = 0.f;
        cg = g;
      }
      gsx += hx; gsy += hy;
    }
  }
  if (h == 0) {
    float* dst = gacc + cg * 256 + loff + c2 * 2;
    atomicAdd(dst + 0, gsx);
    atomicAdd(dst + 1, gsy);
  }
}

// ---------- CSR-ordered edge MLP, SOFTWARE-PIPELINED multi-tile ----------
// Separate xin/hid buffers -> 2 barriers/tile (r7 structure); next tile's
// global loads issued into regs BEFORE GEMM2 so their latency hides under
// compute (T14 issue-early/write-late). Binning + one flush/block as r10.
__global__ __launch_bounds__(256) void mlp_csr_k(
    const u16* __restrict__ hbuf, u16* __restrict__ esrt,
    const int* __restrict__ rowsrt, const int* __restrict__ ebs,
    const u16* __restrict__ W1T, const float* __restrict__ b1,
    const u16* __restrict__ W2T, const float* __restrict__ b2,
    float* __restrict__ gacc, int loff) {
  __shared__ u16 xin[64 * 136];          // 17408B
  __shared__ u16 hid[64 * 136];          // 17408B
  __shared__ float lacc[NGR * 65];       // padded ge-pool bins
  const int t = threadIdx.x;
  const int lane = t & 63;
  const int wave = t >> 6;
  const int m16 = lane & 15;
  const int quad = lane >> 4;
  const int NT = NE / 64;

  for (int i = t; i < NGR * 65; i += 256) lacc[i] = 0.f;

  // ---- preload B fragments + biases (once per block) ----
  bf16x8 B1[2][4], B2[4];
#pragma unroll
  for (int ni = 0; ni < 2; ni++)
#pragma unroll
    for (int ki = 0; ki < 4; ki++)
      B1[ni][ki] = *(const bf16x8*)(W1T + (wave * 32 + ni * 16 + m16) * 128 + ki * 32 + quad * 8);
#pragma unroll
  for (int ki = 0; ki < 4; ki++)
    B2[ki] = *(const bf16x8*)(W2T + (wave * 16 + m16) * 128 + ki * 32 + quad * 8);
  float b1v0 = b1[wave * 32 + m16];
  float b1v1 = b1[wave * 32 + 16 + m16];
  float b2v = b2[wave * 16 + m16];
  const int colo = wave * 16 + m16;
  f32x4 zero = {0.f, 0.f, 0.f, 0.f};

  // staging geometry: thread covers col-chunk c8 (invariant), rows it*16+rw
  const int c8 = (t & 15) * 8;
  const int rw = t >> 4;
  bf16x8 sreg[4];

  // ---- prologue: stage tile0 ----
  int tile = blockIdx.x;
  if (tile < NT) {
    int e0 = tile * 64;
#pragma unroll
    for (int it = 0; it < 4; it++) {
      int r = it * 16 + rw;
      const u16* src = (c8 < 64) ? hbuf + (size_t)rowsrt[e0 + r] * 64 + c8
                                 : esrt + (size_t)(e0 + r) * 64 + (c8 - 64);
      sreg[it] = *(const bf16x8*)src;
    }
#pragma unroll
    for (int it = 0; it < 4; it++)
      *(bf16x8*)&xin[(it * 16 + rw) * 136 + c8] = sreg[it];
  }

  while (tile < NT) {
    const int e0 = tile * 64;
    const int nxt = tile + gridDim.x;
    __syncthreads();                     // sync1: xin(t) ready; G2(t-1) hid reads done

    // ---- GEMM1(t): xin @ W1 -> acc1 ----
    f32x4 acc1[2][4];
#pragma unroll
    for (int ni = 0; ni < 2; ni++)
#pragma unroll
      for (int mi = 0; mi < 4; mi++) acc1[ni][mi] = zero;
#pragma unroll
    for (int ki = 0; ki < 4; ki++) {
#pragma unroll
      for (int mi = 0; mi < 4; mi++) {
        bf16x8 A = *(const bf16x8*)&xin[(mi * 16 + m16) * 136 + ki * 32 + quad * 8];
        acc1[0][mi] = __builtin_amdgcn_mfma_f32_16x16x32_bf16(A, B1[0][ki], acc1[0][mi], 0, 0, 0);
        acc1[1][mi] = __builtin_amdgcn_mfma_f32_16x16x32_bf16(A, B1[1][ki], acc1[1][mi], 0, 0, 0);
      }
    }
    // ---- write hid(t) (separate buffer; G2(t-1) finished before sync1) ----
#pragma unroll
    for (int mi = 0; mi < 4; mi++) {
#pragma unroll
      for (int reg = 0; reg < 4; reg++) {
        int r = mi * 16 + quad * 4 + reg;
        hid[r * 136 + wave * 32 + m16]      = f2bf(fmaxf(acc1[0][mi][reg] + b1v0, 0.f));
        hid[r * 136 + wave * 32 + 16 + m16] = f2bf(fmaxf(acc1[1][mi][reg] + b1v1, 0.f));
      }
    }
    __syncthreads();                     // sync2: hid(t) visible; xin(t) reads done

    // ---- issue stage loads for tile t+1 (latency hides under GEMM2) ----
    if (nxt < NT) {
      int ne0 = nxt * 64;
#pragma unroll
      for (int it = 0; it < 4; it++) {
        int r = it * 16 + rw;
        const u16* src = (c8 < 64) ? hbuf + (size_t)rowsrt[ne0 + r] * 64 + c8
                                   : esrt + (size_t)(ne0 + r) * 64 + (c8 - 64);
        sreg[it] = *(const bf16x8*)src;
      }
    }

    // ---- GEMM2(t): hid @ W2 -> acc2 ----
    f32x4 acc2[4];
#pragma unroll
    for (int mi = 0; mi < 4; mi++) acc2[mi] = zero;
#pragma unroll
    for (int ki = 0; ki < 4; ki++) {
#pragma unroll
      for (int mi = 0; mi < 4; mi++) {
        bf16x8 A = *(const bf16x8*)&hid[(mi * 16 + m16) * 136 + ki * 32 + quad * 8];
        acc2[mi] = __builtin_amdgcn_mfma_f32_16x16x32_bf16(A, B2[ki], acc2[mi], 0, 0, 0);
      }
    }

    // ---- epilogue(t): in-place bf16 esrt write + LDS binning (f32) ----
#pragma unroll
    for (int mi = 0; mi < 4; mi++) {
#pragma unroll
      for (int reg = 0; reg < 4; reg++) {
        int r = mi * 16 + quad * 4 + reg;
        float v = acc2[mi][reg] + b2v;
        esrt[(size_t)(e0 + r) * 64 + colo] = f2bf(v);
        atomicAdd(&lacc[ebs[e0 + r] * 65 + colo], v);
      }
    }

    // ---- write staged regs -> xin(t+1) (xin free since sync2) ----
    if (nxt < NT) {
#pragma unroll
      for (int it = 0; it < 4; it++)
        *(bf16x8*)&xin[(it * 16 + rw) * 136 + c8] = sreg[it];
    }
    tile = nxt;
  }

  // ---- ONE flush per block ----
  __syncthreads();
#pragma unroll
  for (int i = 0; i < 4; i++) {
    int idx = t + 256 * i;               // g = idx>>6, col = idx&63
    float v = lacc[(idx >> 6) * 65 + (idx & 63)];
    if (v != 0.f) atomicAdd(&gacc[(idx >> 6) * 256 + loff + (idx & 63)], v);
  }
}

// ---------- FALLBACK kernels (round-2 proven f32 path, used only if ws too small) ----------
__global__ __launch_bounds__(256) void gather_k(
    const float* __restrict__ ea, const int* __restrict__ off,
    const int* __restrict__ eid, const int* __restrict__ batch,
    float* __restrict__ hbuf, float* __restrict__ gacc,
    int loff, int store_h) {
  int gid = blockIdx.x * blockDim.x + threadIdx.x;
  int w = gid >> 6, lane = gid & 63;
  int nw = (gridDim.x * blockDim.x) >> 6;
  const float* base = ea + lane;
  for (int n = w; n < NN; n += nw) {
    int s = off[n], e = off[n + 1];
    int g = batch[n];
    float a0 = 0.f, a1 = 0.f, a2 = 0.f, a3 = 0.f;
    int i = s;
    for (; i + 4 <= e; i += 4) {
      int e0 = eid[i], e1 = eid[i + 1], e2 = eid[i + 2], e3 = eid[i + 3];
      a0 += base[(size_t)e0 * 64];
      a1 += base[(size_t)e1 * 64];
      a2 += base[(size_t)e2 * 64];
      a3 += base[(size_t)e3 * 64];
    }
    for (; i < e; i++) a0 += base[(size_t)eid[i] * 64];
    float acc = (a0 + a1) + (a2 + a3);
    float hv = acc / (float)max(e - s, 1);
    if (store_h) hbuf[(size_t)n * 64 + lane] = hv;
    atomicAdd(&gacc[g * 256 + loff + lane], hv);
  }
}

__global__ __launch_bounds__(256) void pool_seg_k(const float* __restrict__ ea,
                                                  const int* __restrict__ eoff,
                                                  float* __restrict__ gacc, int loff) {
  int gid = blockIdx.x * blockDim.x + threadIdx.x;
  int w = gid >> 6, lane = gid & 63;
  const int NW = (gridDim.x * blockDim.x) >> 6;
  const int CH = (NE + NW - 1) / NW;
  int r0 = w * CH, r1 = min(r0 + CH, NE);
  if (r0 >= r1) return;
  int g = 0;
  while (eoff[g + 1] <= r0) g++;
  const float* base = ea + lane;
  while (r0 < r1) {
    int gend = min(r1, eoff[g + 1]);
    float a0 = 0.f, a1 = 0.f, a2 = 0.f, a3 = 0.f;
    float a4 = 0.f, a5 = 0.f, a6 = 0.f, a7 = 0.f;
    int r = r0;
    for (; r + 8 <= gend; r += 8) {
      a0 += base[(size_t)(r + 0) * 64];
      a1 += base[(size_t)(r + 1) * 64];
      a2 += base[(size_t)(r + 2) * 64];
      a3 += base[(size_t)(r + 3) * 64];
      a4 += base[(size_t)(r + 4) * 64];
      a5 += base[(size_t)(r + 5) * 64];
      a6 += base[(size_t)(r + 6) * 64];
      a7 += base[(size_t)(r + 7) * 64];
    }
    for (; r < gend; r++) a0 += base[(size_t)r * 64];
    float s = ((a0 + a1) + (a2 + a3)) + ((a4 + a5) + (a6 + a7));
    atomicAdd(&gacc[g * 256 + loff + lane], s);
    r0 = gend;
    g++;
  }
}

__global__ __launch_bounds__(256) void mlp_fallback_k(
    const float* hbuf, float* ea, const int* rowp,
    const u16* W1T, const float* b1,
    const u16* W2T, const float* b2,
    const int* ebatch, float* gacc, int loff) {
  __shared__ u16 sh[2 * 64 * 136];
  u16* xin = sh;
  u16* hid = sh + 64 * 136;
  const int t = threadIdx.x;
  const int e0 = blockIdx.x * 64;
  const int lane = t & 63;
  const int wave = t >> 6;
  const int m16 = lane & 15;
  const int quad = lane >> 4;

  bf16x8 B1[2][4], B2[4];
#pragma unroll
  for (int ni = 0; ni < 2; ni++)
#pragma unroll
    for (int ki = 0; ki < 4; ki++)
      B1[ni][ki] = *(const bf16x8*)(W1T + (wave * 32 + ni * 16 + m16) * 128 + ki * 32 + quad * 8);
#pragma unroll
  for (int ki = 0; ki < 4; ki++)
    B2[ki] = *(const bf16x8*)(W2T + (wave * 16 + m16) * 128 + ki * 32 + quad * 8);

#pragma unroll
  for (int it = 0; it < 8; it++) {
    int f = it * 256 + t;
    int r = f >> 5;
    int c = (f & 31) * 4;
    const float* src;
    if (c < 64) {
      int nd = rowp[e0 + r];
      src = hbuf + (size_t)nd * 64 + c;
    } else {
      src = ea + (size_t)(e0 + r) * 64 + (c - 64);
    }
    float4 v = *(const float4*)src;
    u32 p0 = (u32)f2bf(v.x) | ((u32)f2bf(v.y) << 16);
    u32 p1 = (u32)f2bf(v.z) | ((u32)f2bf(v.w) << 16);
    u32* dst = (u32*)&xin[r * 136 + c];
    dst[0] = p0;
    dst[1] = p1;
  }
  __syncthreads();

  f32x4 zero = {0.f, 0.f, 0.f, 0.f};
  f32x4 acc1[2][4];
#pragma unroll
  for (int ni = 0; ni < 2; ni++)
#pragma unroll
    for (int mi = 0; mi < 4; mi++) acc1[ni][mi] = zero;
#pragma unroll
  for (int ki = 0; ki < 4; ki++) {
#pragma unroll
    for (int mi = 0; mi < 4; mi++) {
      bf16x8 A = *(const bf16x8*)&xin[(mi * 16 + m16) * 136 + ki * 32 + quad * 8];
      acc1[0][mi] = __builtin_amdgcn_mfma_f32_16x16x32_bf16(A, B1[0][ki], acc1[0][mi], 0, 0, 0);
      acc1[1][mi] = __builtin_amdgcn_mfma_f32_16x16x32_bf16(A, B1[1][ki], acc1[1][mi], 0, 0, 0);
    }
  }
  float b1v0 = b1[wave * 32 + m16];
  float b1v1 = b1[wave * 32 + 16 + m16];
#pragma unroll
  for (int mi = 0; mi < 4; mi++) {
#pragma unroll
    for (int reg = 0; reg < 4; reg++) {
      int r = mi * 16 + quad * 4 + reg;
      hid[r * 136 + wave * 32 + m16]      = f2bf(fmaxf(acc1[0][mi][reg] + b1v0, 0.f));
      hid[r * 136 + wave * 32 + 16 + m16] = f2bf(fmaxf(acc1[1][mi][reg] + b1v1, 0.f));
    }
  }
  __syncthreads();

  f32x4 acc2[4];
#pragma unroll
  for (int mi = 0; mi < 4; mi++) acc2[mi] = zero;
#pragma unroll
  for (int ki = 0; ki < 4; ki++) {
#pragma unroll
    for (int mi = 0; mi < 4; mi++) {
      bf16x8 A = *(const bf16x8*)&hid[(mi * 16 + m16) * 136 + ki * 32 + quad * 8];
      acc2[mi] = __builtin_amdgcn_mfma_f32_16x16x32_bf16(A, B2[ki], acc2[mi], 0, 0, 0);
    }
  }
  float b2v = b2[wave * 16 + m16];
#pragma unroll
  for (int mi = 0; mi < 4; mi++) {
#pragma unroll
    for (int reg = 0; reg < 4; reg++) {
      int r = mi * 16 + quad * 4 + reg;
      ea[(size_t)(e0 + r) * 64 + wave * 16 + m16] = acc2[mi][reg] + b2v;
    }
  }
  int g0 = ebatch[e0], g1 = ebatch[e0 + 63];
  int colo = wave * 16 + m16;
  if (g0 == g1) {
    float s = 0.f;
#pragma unroll
    for (int mi = 0; mi < 4; mi++)
#pragma unroll
      for (int reg = 0; reg < 4; reg++) s += acc2[mi][reg] + b2v;
    s += __shfl_xor(s, 16);
    s += __shfl_xor(s, 32);
    if (quad == 0) atomicAdd(&gacc[g0 * 256 + loff + colo], s);
  } else {
#pragma unroll
    for (int mi = 0; mi < 4; mi++)
#pragma unroll
      for (int reg = 0; reg < 4; reg++) {
        int r = mi * 16 + quad * 4 + reg;
        atomicAdd(&gacc[ebatch[e0 + r] * 256 + loff + colo], acc2[mi][reg] + b2v);
      }
  }
}

// ---------- finalize: means (acc already in output layout), head, f32 out ----------
__global__ __launch_bounds__(256) void finalize_k(
    const float* gn_acc, const float* ge_acc,
    const int* cnt_n, const int* cnt_e,
    const float* Wo1, const float* bo1,
    const float* Wo2, const float* bo2,
    const float* Wo3, const float* bo3,
    float* out) {
  __shared__ float attr[16][512];
  __shared__ float o1[16][128];
  __shared__ float o2[16][128];
  int t = threadIdx.x;
  for (int i = t; i < 4096; i += 256) {
    int g = i >> 8, c = i & 255;
    float vn = gn_acc[i] / (float)max(cnt_n[g], 1);
    float ve = ge_acc[i] / (float)max(cnt_e[g], 1);
    out[i] = vn;
    out[4096 + i] = ve;
    attr[g][c] = vn;
    attr[g][256 + c] = ve;
  }
  __syncthreads();
  {
    int j = t & 127, gh = t >> 7;
    float a[8];
#pragma unroll
    for (int q = 0; q < 8; q++) a[q] = bo1[j];
    for (int k = 0; k < 512; k++) {
      float w = Wo1[k * 128 + j];
#pragma unroll
      for (int q = 0; q < 8; q++) a[q] = fmaf(attr[gh * 8 + q][k], w, a[q]);
    }
#pragma unroll
    for (int q = 0; q < 8; q++) o1[gh * 8 + q][j] = fmaxf(a[q], 0.f);
  }
  __syncthreads();
  {
    int j = t & 127, gh = t >> 7;
    float a[8];
#pragma unroll
    for (int q = 0; q < 8; q++) a[q] = bo2[j];
    for (int k = 0; k < 128; k++) {
      float w = Wo2[k * 128 + j];
#pragma unroll
      for (int q = 0; q < 8; q++) a[q] = fmaf(o1[gh * 8 + q][k], w, a[q]);
    }
#pragma unroll
    for (int q = 0; q < 8; q++) o2[gh * 8 + q][j] = fmaxf(a[q], 0.f);
  }
  __syncthreads();
  {
    int j = t & 31, gb = t >> 5;
#pragma unroll
    for (int q = 0; q < 2; q++) {
      int g = gb * 2 + q;
      float a = bo3[j];
      for (int k = 0; k < 128; k++) a = fmaf(o2[g][k], Wo3[k * 32 + j], a);
      out[8192 + g * 32 + j] = a;
    }
  }
}

extern "C" void kernel_launch(void* const* d_in, const int* in_sizes, int n_in,
                              void* d_out, int out_size, void* d_ws, size_t ws_size,
                              hipStream_t stream) {
  float* ea = (float*)d_in[1];               // [NE,64] f32
  const int* edge_index = (const int*)d_in[3];
  const int* row = edge_index;
  const int* col = edge_index + NE;
  const int* batch = (const int*)d_in[4];
  const int* ebatch = (const int*)d_in[5];
  const float* W1s = (const float*)d_in[6];  // [3,128,128]
  const float* b1s = (const float*)d_in[7];  // [3,128]
  const float* W2s = (const float*)d_in[8];  // [3,128,64]
  const float* b2s = (const float*)d_in[9];  // [3,64]
  const float* Wo1 = (const float*)d_in[10];
  const float* bo1 = (const float*)d_in[11];
  const float* Wo2 = (const float*)d_in[12];
  const float* bo2 = (const float*)d_in[13];
  const float* Wo3 = (const float*)d_in[14];
  const float* bo3 = (const float*)d_in[15];

  char* p = (char*)d_ws;
  auto alloc = [&](size_t b) { char* r = p; p += (b + 255) & ~(size_t)255; return r; };
  // ---- zero region (one memset) ----
  int* deg = (int*)alloc(NN * 4);
  int* cursor = (int*)alloc(NN * 4);
  int* cnt_n = (int*)alloc(64);
  int* cnt_e = (int*)alloc(64);
  float* gn_acc = (float*)alloc(NGR * 256 * 4);
  float* ge_acc = (float*)alloc(NGR * 256 * 4);
  size_t zbytes = (size_t)(p - (char*)d_ws);
  // ---- non-zeroed ----
  int* csr_off = (int*)alloc((NN + 1) * 4);
  int* csr_eid = (int*)alloc((size_t)NE * 4);
  int* pos = (int*)alloc((size_t)NE * 4);
  int* rowsrt = (int*)alloc((size_t)NE * 4);
  int* ebs = (int*)alloc((size_t)NE * 4);
  float* hbuf = (float*)alloc((size_t)NN * 64 * 4);   // f32 fallback / bf16 CSR path
  u16* W1T = (u16*)alloc(3 * 128 * 128 * 2);
  u16* W2T = (u16*)alloc(3 * 64 * 128 * 2);
  int* eoff = (int*)alloc((NGR + 1) * 4);
  // esrt: CSR-permuted edge rows, BF16 (102MB) — only if workspace allows
  u16* esrt = nullptr;
  {
    size_t used = (size_t)(p - (char*)d_ws);
    size_t need = (size_t)NE * 64 * 2 + 512;
    if (ws_size >= used + need) esrt = (u16*)alloc((size_t)NE * 64 * 2);
  }

  hipMemsetAsync(d_ws, 0, zbytes, stream);

  prep_w_k<<<(3 * 128 * 128 + 3 * 128 * 64 + 255) / 256, 256, 0, stream>>>(W1s, W2s, W1T, W2T);
  hist_deg<<<(NE + 255) / 256, 256, 0, stream>>>(col, deg);
  count_graphs<<<1, 64, 0, stream>>>(batch, ebatch, cnt_n, cnt_e, eoff);
  scan_deg<<<1, 256, 0, stream>>>(deg, csr_off);
  fill_csr<<<(NE + 255) / 256, 256, 0, stream>>>(col, row, ebatch, csr_off, cursor,
                                                 csr_eid, pos, rowsrt, ebs);

  if (esrt) {
    // ---- CSR-native bf16 path ----
    u16* hbuf_b = (u16*)hbuf;
    pool_perm_k<<<2048, 256, 0, stream>>>(ea, eoff, pos, esrt, ge_acc, 0);
    gather_seq_k<<<4096, 256, 0, stream>>>(esrt, csr_off, batch, hbuf_b, gn_acc, 0, 1);
    for (int l = 0; l < 3; l++) {
      mlp_csr_k<<<2048, 256, 0, stream>>>(hbuf_b, esrt, rowsrt, ebs,
          W1T + l * 16384, b1s + l * 128, W2T + l * 8192, b2s + l * 64,
          ge_acc, (l + 1) * 64);
      gather_seq_k<<<4096, 256, 0, stream>>>(esrt, csr_off, batch, hbuf_b,
                                             gn_acc, (l + 1) * 64, l < 2 ? 1 : 0);
    }
  } else {
    // ---- fallback (round-2 proven f32): random gather via uniform eid ----
    pool_seg_k<<<2048, 256, 0, stream>>>(ea, eoff, ge_acc, 0);
    gather_k<<<2048, 256, 0, stream>>>(ea, csr_off, csr_eid, batch, hbuf, gn_acc, 0, 1);
    for (int l = 0; l < 3; l++) {
      mlp_fallback_k<<<NE / 64, 256, 0, stream>>>(hbuf, ea, row,
          W1T + l * 16384, b1s + l * 128, W2T + l * 8192, b2s + l * 64,
          ebatch, ge_acc, (l + 1) * 64);
      gather_k<<<2048, 256, 0, stream>>>(ea, csr_off, csr_eid, batch, hbuf,
                                         gn_acc, (l + 1) * 64, l < 2 ? 1 : 0);
    }
  }

  finalize_k<<<1, 256, 0, stream>>>(gn_acc, ge_acc, cnt_n, cnt_e,
      Wo1, bo1, Wo2, bo2, Wo3, bo3, (float*)d_out);
}

// Round 13
// 1806.555 us; speedup vs baseline: 1.1603x; 1.1603x over previous
//
#include <hip/hip_runtime.h>

#define NN 50000      // nodes
#define NE 800000     // edges
#define NGR 16        // graphs

typedef unsigned short u16;
typedef unsigned int u32;
typedef __attribute__((ext_vector_type(8))) short bf16x8;
typedef __attribute__((ext_vector_type(4))) float f32x4;

__device__ __forceinline__ u16 f2bf(float f) {       // RNE f32->bf16
  u32 u = __float_as_uint(f);
  return (u16)((u + 0x7fffu + ((u >> 16) & 1u)) >> 16);
}
__device__ __forceinline__ float bflo(u32 v) { return __uint_as_float(v << 16); }
__device__ __forceinline__ float bfhi(u32 v) { return __uint_as_float(v & 0xffff0000u); }

// ---------- degree histogram ----------
__global__ void hist_deg(const int* col, int* deg) {
  int e = blockIdx.x * blockDim.x + threadIdx.x;
  if (e < NE) atomicAdd(&deg[col[e]], 1);
}

// ---------- per-graph counts (sorted ids) + edge segment offsets ----------
__device__ int lbound(const int* a, int n, int v) {
  int lo = 0, hi = n;
  while (lo < hi) { int m = (lo + hi) >> 1; if (a[m] < v) lo = m + 1; else hi = m; }
  return lo;
}
__global__ void count_graphs(const int* batch, const int* ebatch, int* cnt_n, int* cnt_e,
                             int* eoff) {
  int t = threadIdx.x;
  if (t < NGR) cnt_n[t] = lbound(batch, NN, t + 1) - lbound(batch, NN, t);
  else if (t < 2 * NGR) { int g = t - NGR; cnt_e[g] = lbound(ebatch, NE, g + 1) - lbound(ebatch, NE, g); }
  else if (t < 3 * NGR + 1) { int g = t - 2 * NGR; eoff[g] = lbound(ebatch, NE, g); }  // eoff[16]=NE
}

// ---------- exclusive scan of deg -> csr_off (single block) ----------
__global__ __launch_bounds__(256) void scan_deg(const int* deg, int* off) {
  __shared__ int sums[256];
  const int CH = (NN + 255) / 256;
  int t = threadIdx.x;
  int base = t * CH;
  int s = 0;
  for (int i = 0; i < CH; i++) { int idx = base + i; if (idx < NN) s += deg[idx]; }
  sums[t] = s;
  __syncthreads();
  for (int d = 1; d < 256; d <<= 1) {
    int v = (t >= d) ? sums[t - d] : 0;
    __syncthreads();
    sums[t] += v;
    __syncthreads();
  }
  int run = (t == 0) ? 0 : sums[t - 1];
  for (int i = 0; i < CH; i++) { int idx = base + i; if (idx < NN) { off[idx] = run; run += deg[idx]; } }
  if (t == 255) off[NN] = run;
}

// ---------- CSR fill: eid, pos, and CSR-ordered row/graph tables ----------
__global__ void fill_csr(const int* col, const int* rowp, const int* ebatch,
                         const int* off, int* cursor, int* eid, int* pos,
                         int* rowsrt, int* ebs) {
  int e = blockIdx.x * blockDim.x + threadIdx.x;
  if (e < NE) {
    int c = col[e];
    int p = atomicAdd(&cursor[c], 1);
    int slot = off[c] + p;
    eid[slot] = e;
    pos[e] = slot;
    rowsrt[slot] = rowp[e];
    ebs[slot] = ebatch[e];
  }
}

// ---------- weights f32 -> bf16 TRANSPOSED (W1T[l][n][k], W2T[l][n][k]) ----------
__global__ void prep_w_k(const float* W1, const float* W2, u16* W1T, u16* W2T) {
  int i = blockIdx.x * 256 + threadIdx.x;
  if (i < 3 * 128 * 128) {
    int l = i / 16384, k = (i >> 7) & 127, n = i & 127;
    W1T[l * 16384 + n * 128 + k] = f2bf(W1[i]);
  } else {
    int j = i - 3 * 128 * 128;
    if (j < 3 * 128 * 64) {
      int l = j / 8192, k = (j >> 6) & 127, n = j & 63;
      W2T[l * 8192 + n * 128 + k] = f2bf(W2[j]);
    }
  }
}

// ---------- layer-0: segmented ge pool (f32) + CSR permute -> esrt BF16 ----------
__global__ __launch_bounds__(256) void pool_perm_k(const float* __restrict__ ea,
                                                   const int* __restrict__ eoff,
                                                   const int* __restrict__ pos,
                                                   u16* __restrict__ esrt,
                                                   float* __restrict__ gacc, int loff) {
  int gid = blockIdx.x * blockDim.x + threadIdx.x;
  int w = gid >> 6, lane = gid & 63;
  const int NW = (gridDim.x * blockDim.x) >> 6;
  const int CH = (NE + NW - 1) / NW;
  int r0 = w * CH, r1 = min(r0 + CH, NE);
  if (r0 >= r1) return;
  int g = 0;
  while (eoff[g + 1] <= r0) g++;       // <=16 scalar iters, once per wave
  const float* base = ea + lane;
  u16* sbase = esrt + lane;
  while (r0 < r1) {
    int gend = min(r1, eoff[g + 1]);
    float a0 = 0.f, a1 = 0.f, a2 = 0.f, a3 = 0.f;
    float a4 = 0.f, a5 = 0.f, a6 = 0.f, a7 = 0.f;
    int r = r0;
    for (; r + 8 <= gend; r += 8) {
      float v0 = base[(size_t)(r + 0) * 64];
      float v1 = base[(size_t)(r + 1) * 64];
      float v2 = base[(size_t)(r + 2) * 64];
      float v3 = base[(size_t)(r + 3) * 64];
      float v4 = base[(size_t)(r + 4) * 64];
      float v5 = base[(size_t)(r + 5) * 64];
      float v6 = base[(size_t)(r + 6) * 64];
      float v7 = base[(size_t)(r + 7) * 64];
      sbase[(size_t)pos[r + 0] * 64] = f2bf(v0);
      sbase[(size_t)pos[r + 1] * 64] = f2bf(v1);
      sbase[(size_t)pos[r + 2] * 64] = f2bf(v2);
      sbase[(size_t)pos[r + 3] * 64] = f2bf(v3);
      sbase[(size_t)pos[r + 4] * 64] = f2bf(v4);
      sbase[(size_t)pos[r + 5] * 64] = f2bf(v5);
      sbase[(size_t)pos[r + 6] * 64] = f2bf(v6);
      sbase[(size_t)pos[r + 7] * 64] = f2bf(v7);
      a0 += v0; a1 += v1; a2 += v2; a3 += v3;
      a4 += v4; a5 += v5; a6 += v6; a7 += v7;
    }
    for (; r < gend; r++) {
      float v = base[(size_t)r * 64];
      sbase[(size_t)pos[r] * 64] = f2bf(v);
      a0 += v;
    }
    float s = ((a0 + a1) + (a2 + a3)) + ((a4 + a5) + (a6 + a7));
    atomicAdd(&gacc[g * 256 + loff + lane], s);
    r0 = gend;
    g++;
  }
}

// ---------- STREAMING gather (bf16) + optional fused ge-pool ----------
// Streams every esrt row once anyway; ge-binning (order-insensitive, per-row
// LDS atomics into padded bins, one flush/block) rides on idle VALU/LDS here
// instead of the mlp critical path. No sortedness assumption on ebs.
__global__ __launch_bounds__(256) void gather_seq_k(
    const u16* __restrict__ esrt, const int* __restrict__ off,
    const int* __restrict__ batch, const int* __restrict__ ebs,
    u16* __restrict__ hbuf,
    float* __restrict__ gacc, int loff, int store_h,
    float* __restrict__ geacc, int ge_loff, int do_ge) {
  __shared__ float lacc[NGR * 65];
  int gid = blockIdx.x * blockDim.x + threadIdx.x;
  int w = gid >> 6, lane = gid & 63;
  const int NW = (gridDim.x * blockDim.x) >> 6;
  const int CHN = (NN + NW - 1) / NW;
  int n0 = w * CHN, n1 = min(n0 + CHN, NN);
  int h = lane >> 5, c2 = lane & 31;       // col pair (2*c2, 2*c2+1)
  const int cx = c2 * 2;
  if (do_ge) {
    for (int i = threadIdx.x; i < NGR * 65; i += 256) lacc[i] = 0.f;
    __syncthreads();
  }
  const u32* base = (const u32*)esrt + c2; // row stride = 32 u32
  if (n0 < n1) {
    int cg = batch[n0];
    float gsx = 0.f, gsy = 0.f;
    for (int n = n0; n < n1; n++) {
      int s = off[n], e = off[n + 1];
      float x0 = 0.f, y0 = 0.f, x1 = 0.f, y1 = 0.f;
      float x2 = 0.f, y2 = 0.f, x3 = 0.f, y3 = 0.f;
      int i = s;
      for (; i + 8 <= e; i += 8) {         // 8 rows/iter, this half loads 4
        int r0 = i + 0 + h, r1 = i + 2 + h, r2 = i + 4 + h, r3 = i + 6 + h;
        u32 v0 = base[(size_t)r0 * 32];
        u32 v1 = base[(size_t)r1 * 32];
        u32 v2 = base[(size_t)r2 * 32];
        u32 v3 = base[(size_t)r3 * 32];
        if (do_ge) {
          atomicAdd(&lacc[ebs[r0] * 65 + cx],     bflo(v0));
          atomicAdd(&lacc[ebs[r0] * 65 + cx + 1], bfhi(v0));
          atomicAdd(&lacc[ebs[r1] * 65 + cx],     bflo(v1));
          atomicAdd(&lacc[ebs[r1] * 65 + cx + 1], bfhi(v1));
          atomicAdd(&lacc[ebs[r2] * 65 + cx],     bflo(v2));
          atomicAdd(&lacc[ebs[r2] * 65 + cx + 1], bfhi(v2));
          atomicAdd(&lacc[ebs[r3] * 65 + cx],     bflo(v3));
          atomicAdd(&lacc[ebs[r3] * 65 + cx + 1], bfhi(v3));
        }
        x0 += bflo(v0); y0 += bfhi(v0);
        x1 += bflo(v1); y1 += bfhi(v1);
        x2 += bflo(v2); y2 += bfhi(v2);
        x3 += bflo(v3); y3 += bfhi(v3);
      }
      for (; i + 2 <= e; i += 2) {
        int r0 = i + h;
        u32 v = base[(size_t)r0 * 32];
        if (do_ge) {
          atomicAdd(&lacc[ebs[r0] * 65 + cx],     bflo(v));
          atomicAdd(&lacc[ebs[r0] * 65 + cx + 1], bfhi(v));
        }
        x0 += bflo(v); y0 += bfhi(v);
      }
      if (i < e && h == 0) {
        u32 v = base[(size_t)i * 32];
        if (do_ge) {
          atomicAdd(&lacc[ebs[i] * 65 + cx],     bflo(v));
          atomicAdd(&lacc[ebs[i] * 65 + cx + 1], bfhi(v));
        }
        x0 += bflo(v); y0 += bfhi(v);
      }
      float sx = (x0 + x1) + (x2 + x3);
      float sy = (y0 + y1) + (y2 + y3);
      sx += __shfl_xor(sx, 32);
      sy += __shfl_xor(sy, 32);
      if (h == 0) {
        float inv = 1.f / (float)max(e - s, 1);
        float hx = sx * inv, hy = sy * inv;
        if (store_h)
          ((u32*)hbuf)[(size_t)n * 32 + c2] = (u32)f2bf(hx) | ((u32)f2bf(hy) << 16);
        int g = batch[n];                  // uniform scalar load
        if (g != cg) {
          float* dst = gacc + cg * 256 + loff + cx;
          atomicAdd(dst + 0, gsx);
          atomicAdd(dst + 1, gsy);
          gsx = 0.f; gsy = 0.f;
          cg = g;
        }
        gsx += hx; gsy += hy;
      }
    }
    if (h == 0) {
      float* dst = gacc + cg * 256 + loff + cx;
      atomicAdd(dst + 0, gsx);
      atomicAdd(dst + 1, gsy);
    }
  }
  if (do_ge) {
    __syncthreads();                       // all threads reach this (no early return)
    for (int i = threadIdx.x; i < NGR * 64; i += 256) {
      int g = i >> 6, c = i & 63;
      float v = lacc[g * 65 + c];
      if (v != 0.f) atomicAdd(&geacc[g * 256 + ge_loff + c], v);
    }
  }
}

// ---------- CSR-ordered edge MLP (bf16), MULTI-TILE grid-stride (r10 struct) ----------
// Pure compute+store: staging 16B copies, overlay xin/hid, in-place esrt write.
// ge-pool moved to gather_seq_k.
__global__ __launch_bounds__(256) void mlp_csr_k(
    const u16* __restrict__ hbuf, u16* __restrict__ esrt,
    const int* __restrict__ rowsrt,
    const u16* __restrict__ W1T, const float* __restrict__ b1,
    const u16* __restrict__ W2T, const float* __restrict__ b2) {
  __shared__ u16 sh[64 * 136];           // 17408B: xin overlays hid
  u16* xin = sh;
  u16* hid = sh;
  const int t = threadIdx.x;
  const int lane = t & 63;
  const int wave = t >> 6;
  const int m16 = lane & 15;
  const int quad = lane >> 4;

  // ---- preload B fragments + biases (once per block) ----
  bf16x8 B1[2][4], B2[4];
#pragma unroll
  for (int ni = 0; ni < 2; ni++)
#pragma unroll
    for (int ki = 0; ki < 4; ki++)
      B1[ni][ki] = *(const bf16x8*)(W1T + (wave * 32 + ni * 16 + m16) * 128 + ki * 32 + quad * 8);
#pragma unroll
  for (int ki = 0; ki < 4; ki++)
    B2[ki] = *(const bf16x8*)(W2T + (wave * 16 + m16) * 128 + ki * 32 + quad * 8);
  float b1v0 = b1[wave * 32 + m16];
  float b1v1 = b1[wave * 32 + 16 + m16];
  float b2v = b2[wave * 16 + m16];
  const int colo = wave * 16 + m16;
  f32x4 zero = {0.f, 0.f, 0.f, 0.f};

  for (int tile = blockIdx.x; tile < NE / 64; tile += gridDim.x) {
    const int e0 = tile * 64;
    __syncthreads();                     // prev tile's hid reads done

    // ---- stage xin[64][128] bf16 = [hbuf[rowsrt[i]], esrt[i]] : 4x 16B copies ----
#pragma unroll
    for (int it = 0; it < 4; it++) {
      int f = it * 256 + t;              // 16B-chunk id 0..1023
      int r = f >> 4;                    // row 0..63
      int c8 = (f & 15) * 8;             // col base 0..120 (thread-invariant)
      const u16* src;
      if (c8 < 64) {
        src = hbuf + (size_t)rowsrt[e0 + r] * 64 + c8;
      } else {
        src = esrt + (size_t)(e0 + r) * 64 + (c8 - 64);
      }
      *(bf16x8*)&xin[r * 136 + c8] = *(const bf16x8*)src;
    }
    __syncthreads();

    // ---- GEMM1 -> acc1 (regs) ----
    f32x4 acc1[2][4];
#pragma unroll
    for (int ni = 0; ni < 2; ni++)
#pragma unroll
      for (int mi = 0; mi < 4; mi++) acc1[ni][mi] = zero;
#pragma unroll
    for (int ki = 0; ki < 4; ki++) {
#pragma unroll
      for (int mi = 0; mi < 4; mi++) {
        bf16x8 A = *(const bf16x8*)&xin[(mi * 16 + m16) * 136 + ki * 32 + quad * 8];
        acc1[0][mi] = __builtin_amdgcn_mfma_f32_16x16x32_bf16(A, B1[0][ki], acc1[0][mi], 0, 0, 0);
        acc1[1][mi] = __builtin_amdgcn_mfma_f32_16x16x32_bf16(A, B1[1][ki], acc1[1][mi], 0, 0, 0);
      }
    }
    __syncthreads();                     // xin reads done before hid overwrite

#pragma unroll
    for (int mi = 0; mi < 4; mi++) {
#pragma unroll
      for (int reg = 0; reg < 4; reg++) {
        int r = mi * 16 + quad * 4 + reg;
        hid[r * 136 + wave * 32 + m16]      = f2bf(fmaxf(acc1[0][mi][reg] + b1v0, 0.f));
        hid[r * 136 + wave * 32 + 16 + m16] = f2bf(fmaxf(acc1[1][mi][reg] + b1v1, 0.f));
      }
    }
    __syncthreads();

    // ---- GEMM2 -> acc2 ----
    f32x4 acc2[4];
#pragma unroll
    for (int mi = 0; mi < 4; mi++) acc2[mi] = zero;
#pragma unroll
    for (int ki = 0; ki < 4; ki++) {
#pragma unroll
      for (int mi = 0; mi < 4; mi++) {
        bf16x8 A = *(const bf16x8*)&hid[(mi * 16 + m16) * 136 + ki * 32 + quad * 8];
        acc2[mi] = __builtin_amdgcn_mfma_f32_16x16x32_bf16(A, B2[ki], acc2[mi], 0, 0, 0);
      }
    }

    // ---- in-place bf16 esrt write ----
#pragma unroll
    for (int mi = 0; mi < 4; mi++) {
#pragma unroll
      for (int reg = 0; reg < 4; reg++) {
        int r = mi * 16 + quad * 4 + reg;
        esrt[(size_t)(e0 + r) * 64 + colo] = f2bf(acc2[mi][reg] + b2v);
      }
    }
  }
}

// ---------- FALLBACK kernels (round-2 proven f32 path, used only if ws too small) ----------
__global__ __launch_bounds__(256) void gather_k(
    const float* __restrict__ ea, const int* __restrict__ off,
    const int* __restrict__ eid, const int* __restrict__ batch,
    float* __restrict__ hbuf, float* __restrict__ gacc,
    int loff, int store_h) {
  int gid = blockIdx.x * blockDim.x + threadIdx.x;
  int w = gid >> 6, lane = gid & 63;
  int nw = (gridDim.x * blockDim.x) >> 6;
  const float* base = ea + lane;
  for (int n = w; n < NN; n += nw) {
    int s = off[n], e = off[n + 1];
    int g = batch[n];
    float a0 = 0.f, a1 = 0.f, a2 = 0.f, a3 = 0.f;
    int i = s;
    for (; i + 4 <= e; i += 4) {
      int e0 = eid[i], e1 = eid[i + 1], e2 = eid[i + 2], e3 = eid[i + 3];
      a0 += base[(size_t)e0 * 64];
      a1 += base[(size_t)e1 * 64];
      a2 += base[(size_t)e2 * 64];
      a3 += base[(size_t)e3 * 64];
    }
    for (; i < e; i++) a0 += base[(size_t)eid[i] * 64];
    float acc = (a0 + a1) + (a2 + a3);
    float hv = acc / (float)max(e - s, 1);
    if (store_h) hbuf[(size_t)n * 64 + lane] = hv;
    atomicAdd(&gacc[g * 256 + loff + lane], hv);
  }
}

__global__ __launch_bounds__(256) void pool_seg_k(const float* __restrict__ ea,
                                                  const int* __restrict__ eoff,
                                                  float* __restrict__ gacc, int loff) {
  int gid = blockIdx.x * blockDim.x + threadIdx.x;
  int w = gid >> 6, lane = gid & 63;
  const int NW = (gridDim.x * blockDim.x) >> 6;
  const int CH = (NE + NW - 1) / NW;
  int r0 = w * CH, r1 = min(r0 + CH, NE);
  if (r0 >= r1) return;
  int g = 0;
  while (eoff[g + 1] <= r0) g++;
  const float* base = ea + lane;
  while (r0 < r1) {
    int gend = min(r1, eoff[g + 1]);
    float a0 = 0.f, a1 = 0.f, a2 = 0.f, a3 = 0.f;
    float a4 = 0.f, a5 = 0.f, a6 = 0.f, a7 = 0.f;
    int r = r0;
    for (; r + 8 <= gend; r += 8) {
      a0 += base[(size_t)(r + 0) * 64];
      a1 += base[(size_t)(r + 1) * 64];
      a2 += base[(size_t)(r + 2) * 64];
      a3 += base[(size_t)(r + 3) * 64];
      a4 += base[(size_t)(r + 4) * 64];
      a5 += base[(size_t)(r + 5) * 64];
      a6 += base[(size_t)(r + 6) * 64];
      a7 += base[(size_t)(r + 7) * 64];
    }
    for (; r < gend; r++) a0 += base[(size_t)r * 64];
    float s = ((a0 + a1) + (a2 + a3)) + ((a4 + a5) + (a6 + a7));
    atomicAdd(&gacc[g * 256 + loff + lane], s);
    r0 = gend;
    g++;
  }
}

__global__ __launch_bounds__(256) void mlp_fallback_k(
    const float* hbuf, float* ea, const int* rowp,
    const u16* W1T, const float* b1,
    const u16* W2T, const float* b2,
    const int* ebatch, float* gacc, int loff) {
  __shared__ u16 sh[2 * 64 * 136];
  u16* xin = sh;
  u16* hid = sh + 64 * 136;
  const int t = threadIdx.x;
  const int e0 = blockIdx.x * 64;
  const int lane = t & 63;
  const int wave = t >> 6;
  const int m16 = lane & 15;
  const int quad = lane >> 4;

  bf16x8 B1[2][4], B2[4];
#pragma unroll
  for (int ni = 0; ni < 2; ni++)
#pragma unroll
    for (int ki = 0; ki < 4; ki++)
      B1[ni][ki] = *(const bf16x8*)(W1T + (wave * 32 + ni * 16 + m16) * 128 + ki * 32 + quad * 8);
#pragma unroll
  for (int ki = 0; ki < 4; ki++)
    B2[ki] = *(const bf16x8*)(W2T + (wave * 16 + m16) * 128 + ki * 32 + quad * 8);

#pragma unroll
  for (int it = 0; it < 8; it++) {
    int f = it * 256 + t;
    int r = f >> 5;
    int c = (f & 31) * 4;
    const float* src;
    if (c < 64) {
      int nd = rowp[e0 + r];
      src = hbuf + (size_t)nd * 64 + c;
    } else {
      src = ea + (size_t)(e0 + r) * 64 + (c - 64);
    }
    float4 v = *(const float4*)src;
    u32 p0 = (u32)f2bf(v.x) | ((u32)f2bf(v.y) << 16);
    u32 p1 = (u32)f2bf(v.z) | ((u32)f2bf(v.w) << 16);
    u32* dst = (u32*)&xin[r * 136 + c];
    dst[0] = p0;
    dst[1] = p1;
  }
  __syncthreads();

  f32x4 zero = {0.f, 0.f, 0.f, 0.f};
  f32x4 acc1[2][4];
#pragma unroll
  for (int ni = 0; ni < 2; ni++)
#pragma unroll
    for (int mi = 0; mi < 4; mi++) acc1[ni][mi] = zero;
#pragma unroll
  for (int ki = 0; ki < 4; ki++) {
#pragma unroll
    for (int mi = 0; mi < 4; mi++) {
      bf16x8 A = *(const bf16x8*)&xin[(mi * 16 + m16) * 136 + ki * 32 + quad * 8];
      acc1[0][mi] = __builtin_amdgcn_mfma_f32_16x16x32_bf16(A, B1[0][ki], acc1[0][mi], 0, 0, 0);
      acc1[1][mi] = __builtin_amdgcn_mfma_f32_16x16x32_bf16(A, B1[1][ki], acc1[1][mi], 0, 0, 0);
    }
  }
  float b1v0 = b1[wave * 32 + m16];
  float b1v1 = b1[wave * 32 + 16 + m16];
#pragma unroll
  for (int mi = 0; mi < 4; mi++) {
#pragma unroll
    for (int reg = 0; reg < 4; reg++) {
      int r = mi * 16 + quad * 4 + reg;
      hid[r * 136 + wave * 32 + m16]      = f2bf(fmaxf(acc1[0][mi][reg] + b1v0, 0.f));
      hid[r * 136 + wave * 32 + 16 + m16] = f2bf(fmaxf(acc1[1][mi][reg] + b1v1, 0.f));
    }
  }
  __syncthreads();

  f32x4 acc2[4];
#pragma unroll
  for (int mi = 0; mi < 4; mi++) acc2[mi] = zero;
#pragma unroll
  for (int ki = 0; ki < 4; ki++) {
#pragma unroll
    for (int mi = 0; mi < 4; mi++) {
      bf16x8 A = *(const bf16x8*)&hid[(mi * 16 + m16) * 136 + ki * 32 + quad * 8];
      acc2[mi] = __builtin_amdgcn_mfma_f32_16x16x32_bf16(A, B2[ki], acc2[mi], 0, 0, 0);
    }
  }
  float b2v = b2[wave * 16 + m16];
#pragma unroll
  for (int mi = 0; mi < 4; mi++) {
#pragma unroll
    for (int reg = 0; reg < 4; reg++) {
      int r = mi * 16 + quad * 4 + reg;
      ea[(size_t)(e0 + r) * 64 + wave * 16 + m16] = acc2[mi][reg] + b2v;
    }
  }
  int g0 = ebatch[e0], g1 = ebatch[e0 + 63];
  int colo = wave * 16 + m16;
  if (g0 == g1) {
    float s = 0.f;
#pragma unroll
    for (int mi = 0; mi < 4; mi++)
#pragma unroll
      for (int reg = 0; reg < 4; reg++) s += acc2[mi][reg] + b2v;
    s += __shfl_xor(s, 16);
    s += __shfl_xor(s, 32);
    if (quad == 0) atomicAdd(&gacc[g0 * 256 + loff + colo], s);
  } else {
#pragma unroll
    for (int mi = 0; mi < 4; mi++)
#pragma unroll
      for (int reg = 0; reg < 4; reg++) {
        int r = mi * 16 + quad * 4 + reg;
        atomicAdd(&gacc[ebatch[e0 + r] * 256 + loff + colo], acc2[mi][reg] + b2v);
      }
  }
}

// ---------- finalize: means (acc already in output layout), head, f32 out ----------
__global__ __launch_bounds__(256) void finalize_k(
    const float* gn_acc, const float* ge_acc,
    const int* cnt_n, const int* cnt_e,
    const float* Wo1, const float* bo1,
    const float* Wo2, const float* bo2,
    const float* Wo3, const float* bo3,
    float* out) {
  __shared__ float attr[16][512];
  __shared__ float o1[16][128];
  __shared__ float o2[16][128];
  int t = threadIdx.x;
  for (int i = t; i < 4096; i += 256) {
    int g = i >> 8, c = i & 255;
    float vn = gn_acc[i] / (float)max(cnt_n[g], 1);
    float ve = ge_acc[i] / (float)max(cnt_e[g], 1);
    out[i] = vn;
    out[4096 + i] = ve;
    attr[g][c] = vn;
    attr[g][256 + c] = ve;
  }
  __syncthreads();
  {
    int j = t & 127, gh = t >> 7;
    float a[8];
#pragma unroll
    for (int q = 0; q < 8; q++) a[q] = bo1[j];
    for (int k = 0; k < 512; k++) {
      float w = Wo1[k * 128 + j];
#pragma unroll
      for (int q = 0; q < 8; q++) a[q] = fmaf(attr[gh * 8 + q][k], w, a[q]);
    }
#pragma unroll
    for (int q = 0; q < 8; q++) o1[gh * 8 + q][j] = fmaxf(a[q], 0.f);
  }
  __syncthreads();
  {
    int j = t & 127, gh = t >> 7;
    float a[8];
#pragma unroll
    for (int q = 0; q < 8; q++) a[q] = bo2[j];
    for (int k = 0; k < 128; k++) {
      float w = Wo2[k * 128 + j];
#pragma unroll
      for (int q = 0; q < 8; q++) a[q] = fmaf(o1[gh * 8 + q][k], w, a[q]);
    }
#pragma unroll
    for (int q = 0; q < 8; q++) o2[gh * 8 + q][j] = fmaxf(a[q], 0.f);
  }
  __syncthreads();
  {
    int j = t & 31, gb = t >> 5;
#pragma unroll
    for (int q = 0; q < 2; q++) {
      int g = gb * 2 + q;
      float a = bo3[j];
      for (int k = 0; k < 128; k++) a = fmaf(o2[g][k], Wo3[k * 32 + j], a);
      out[8192 + g * 32 + j] = a;
    }
  }
}

extern "C" void kernel_launch(void* const* d_in, const int* in_sizes, int n_in,
                              void* d_out, int out_size, void* d_ws, size_t ws_size,
                              hipStream_t stream) {
  float* ea = (float*)d_in[1];               // [NE,64] f32
  const int* edge_index = (const int*)d_in[3];
  const int* row = edge_index;
  const int* col = edge_index + NE;
  const int* batch = (const int*)d_in[4];
  const int* ebatch = (const int*)d_in[5];
  const float* W1s = (const float*)d_in[6];  // [3,128,128]
  const float* b1s = (const float*)d_in[7];  // [3,128]
  const float* W2s = (const float*)d_in[8];  // [3,128,64]
  const float* b2s = (const float*)d_in[9];  // [3,64]
  const float* Wo1 = (const float*)d_in[10];
  const float* bo1 = (const float*)d_in[11];
  const float* Wo2 = (const float*)d_in[12];
  const float* bo2 = (const float*)d_in[13];
  const float* Wo3 = (const float*)d_in[14];
  const float* bo3 = (const float*)d_in[15];

  char* p = (char*)d_ws;
  auto alloc = [&](size_t b) { char* r = p; p += (b + 255) & ~(size_t)255; return r; };
  // ---- zero region (one memset) ----
  int* deg = (int*)alloc(NN * 4);
  int* cursor = (int*)alloc(NN * 4);
  int* cnt_n = (int*)alloc(64);
  int* cnt_e = (int*)alloc(64);
  float* gn_acc = (float*)alloc(NGR * 256 * 4);
  float* ge_acc = (float*)alloc(NGR * 256 * 4);
  size_t zbytes = (size_t)(p - (char*)d_ws);
  // ---- non-zeroed ----
  int* csr_off = (int*)alloc((NN + 1) * 4);
  int* csr_eid = (int*)alloc((size_t)NE * 4);
  int* pos = (int*)alloc((size_t)NE * 4);
  int* rowsrt = (int*)alloc((size_t)NE * 4);
  int* ebs = (int*)alloc((size_t)NE * 4);
  float* hbuf = (float*)alloc((size_t)NN * 64 * 4);   // f32 fallback / bf16 CSR path
  u16* W1T = (u16*)alloc(3 * 128 * 128 * 2);
  u16* W2T = (u16*)alloc(3 * 64 * 128 * 2);
  int* eoff = (int*)alloc((NGR + 1) * 4);
  // esrt: CSR-permuted edge rows, BF16 (102MB) — only if workspace allows
  u16* esrt = nullptr;
  {
    size_t used = (size_t)(p - (char*)d_ws);
    size_t need = (size_t)NE * 64 * 2 + 512;
    if (ws_size >= used + need) esrt = (u16*)alloc((size_t)NE * 64 * 2);
  }

  hipMemsetAsync(d_ws, 0, zbytes, stream);

  prep_w_k<<<(3 * 128 * 128 + 3 * 128 * 64 + 255) / 256, 256, 0, stream>>>(W1s, W2s, W1T, W2T);
  hist_deg<<<(NE + 255) / 256, 256, 0, stream>>>(col, deg);
  count_graphs<<<1, 64, 0, stream>>>(batch, ebatch, cnt_n, cnt_e, eoff);
  scan_deg<<<1, 256, 0, stream>>>(deg, csr_off);
  fill_csr<<<(NE + 255) / 256, 256, 0, stream>>>(col, row, ebatch, csr_off, cursor,
                                                 csr_eid, pos, rowsrt, ebs);

  if (esrt) {
    // ---- CSR-native bf16 path ----
    u16* hbuf_b = (u16*)hbuf;
    pool_perm_k<<<2048, 256, 0, stream>>>(ea, eoff, pos, esrt, ge_acc, 0);
    gather_seq_k<<<2048, 256, 0, stream>>>(esrt, csr_off, batch, ebs, hbuf_b,
                                           gn_acc, 0, 1, ge_acc, 0, 0);
    for (int l = 0; l < 3; l++) {
      mlp_csr_k<<<2048, 256, 0, stream>>>(hbuf_b, esrt, rowsrt,
          W1T + l * 16384, b1s + l * 128, W2T + l * 8192, b2s + l * 64);
      gather_seq_k<<<2048, 256, 0, stream>>>(esrt, csr_off, batch, ebs, hbuf_b,
                                             gn_acc, (l + 1) * 64, l < 2 ? 1 : 0,
                                             ge_acc, (l + 1) * 64, 1);
    }
  } else {
    // ---- fallback (round-2 proven f32): random gather via uniform eid ----
    pool_seg_k<<<2048, 256, 0, stream>>>(ea, eoff, ge_acc, 0);
    gather_k<<<2048, 256, 0, stream>>>(ea, csr_off, csr_eid, batch, hbuf, gn_acc, 0, 1);
    for (int l = 0; l < 3; l++) {
      mlp_fallback_k<<<NE / 64, 256, 0, stream>>>(hbuf, ea, row,
          W1T + l * 16384, b1s + l * 128, W2T + l * 8192, b2s + l * 64,
          ebatch, ge_acc, (l + 1) * 64);
      gather_k<<<2048, 256, 0, stream>>>(ea, csr_off, csr_eid, batch, hbuf,
                                         gn_acc, (l + 1) * 64, l < 2 ? 1 : 0);
    }
  }

  finalize_k<<<1, 256, 0, stream>>>(gn_acc, ge_acc, cnt_n, cnt_e,
      Wo1, bo1, Wo2, bo2, Wo3, bo3, (float*)d_out);
}